// Round 1
// baseline (498.673 us; speedup 1.0000x reference)
//
#include <hip/hip_runtime.h>
#include <stdint.h>
#include <stddef.h>

#define NN 8192      // nodes
#define KD 256       // in_dim
#define CD 256       // out_dim*heads
#define FD 128       // out_dim
#define BI 32        // i-tile rows per block (k_gat)
#define BJ 64        // j-tile

typedef __attribute__((ext_vector_type(4))) float f32x4;
typedef __attribute__((ext_vector_type(8))) short b16x8;

__device__ __forceinline__ unsigned short f2bf(float x) {
    unsigned int u = __float_as_uint(x);
    u += 0x7fffu + ((u >> 16) & 1u);
    return (unsigned short)(u >> 16);
}

// ---------------------------------------------------------------------------
// Kernel 1: T = feat @ W.T (bf16 MFMA) fused with:
//   - scores s[n,h], d[n,h] from fp32 accumulators (shfl reduce)
//   - transposed bf16 output Tt[c][n]
// grid=128, block=256
// ---------------------------------------------------------------------------
__global__ __launch_bounds__(256) void k_transform(
    const float* __restrict__ feat, const float* __restrict__ W,
    const float* __restrict__ asrc, const float* __restrict__ adst,
    unsigned short* __restrict__ Tt, float* __restrict__ s, float* __restrict__ d)
{
    __shared__ unsigned short a_lds[64 * 32];    // 4KB
    __shared__ unsigned short b_lds[256 * 32];   // 16KB
    __shared__ unsigned short tr_lds[256 * 72];  // 36KB (stride 72 = 144B: 16B-aligned rows, no conflicts)
    __shared__ float sc_lds[4][64];              // 1KB
    __shared__ float dc_lds[4][64];              // 1KB

    const int t = threadIdx.x;
    const int wave = t >> 6, lane = t & 63;
    const int l15 = lane & 15, quad = lane >> 4;
    const int n0 = blockIdx.x * 64;
    const int ai = t >> 2, ag = t & 3;

    f32x4 acc[4][4] = {};
    for (int kc = 0; kc < 8; ++kc) {
        const int k0 = kc * 32;
        __syncthreads();
        { // stage A: features[n0+ai][k0 + ag*8 .. +7] -> bf16
            const float* src = feat + (size_t)(n0 + ai) * KD + k0 + ag * 8;
            const float4 v0 = *(const float4*)src;
            const float4 v1 = *(const float4*)(src + 4);
            union { unsigned short us[8]; b16x8 v; } pk;
            pk.us[0] = f2bf(v0.x); pk.us[1] = f2bf(v0.y);
            pk.us[2] = f2bf(v0.z); pk.us[3] = f2bf(v0.w);
            pk.us[4] = f2bf(v1.x); pk.us[5] = f2bf(v1.y);
            pk.us[6] = f2bf(v1.z); pk.us[7] = f2bf(v1.w);
            const int slot = ag ^ ((ai >> 1) & 3);
            *(b16x8*)&a_lds[ai * 32 + slot * 8] = pk.v;
        }
        for (int p = 0; p < 4; ++p) { // stage B: W[c][k0 + g*8 .. +7]
            const int G = p * 256 + t;
            const int c = G >> 2, g = G & 3;
            const float* src = W + (size_t)c * KD + k0 + g * 8;
            const float4 v0 = *(const float4*)src;
            const float4 v1 = *(const float4*)(src + 4);
            union { unsigned short us[8]; b16x8 v; } pk;
            pk.us[0] = f2bf(v0.x); pk.us[1] = f2bf(v0.y);
            pk.us[2] = f2bf(v0.z); pk.us[3] = f2bf(v0.w);
            pk.us[4] = f2bf(v1.x); pk.us[5] = f2bf(v1.y);
            pk.us[6] = f2bf(v1.z); pk.us[7] = f2bf(v1.w);
            const int slot = g ^ ((c >> 1) & 3);
            *(b16x8*)&b_lds[c * 32 + slot * 8] = pk.v;
        }
        __syncthreads();
        b16x8 af[4], bfr[4];
        for (int mt = 0; mt < 4; ++mt) {
            const int m = mt * 16 + l15;
            af[mt] = *(const b16x8*)&a_lds[m * 32 + (quad ^ ((m >> 1) & 3)) * 8];
        }
        for (int nt = 0; nt < 4; ++nt) {
            const int c = wave * 64 + nt * 16 + l15;
            bfr[nt] = *(const b16x8*)&b_lds[c * 32 + (quad ^ ((c >> 1) & 3)) * 8];
        }
        for (int mt = 0; mt < 4; ++mt)
            for (int nt = 0; nt < 4; ++nt)
                acc[mt][nt] = __builtin_amdgcn_mfma_f32_16x16x32_bf16(
                    af[mt], bfr[nt], acc[mt][nt], 0, 0, 0);
    }

    // ---- epilogue: scores (fp32) + transposed bf16 store ----
    float aS[4], aD[4];
    for (int nt = 0; nt < 4; ++nt) {
        const int c = wave * 64 + nt * 16 + l15;
        aS[nt] = asrc[c]; aD[nt] = adst[c];
    }
    for (int mt = 0; mt < 4; ++mt)
        for (int r = 0; r < 4; ++r) {
            float vs = 0.f, vd = 0.f;
            for (int nt = 0; nt < 4; ++nt) {
                const float x = acc[mt][nt][r];
                vs += x * aS[nt]; vd += x * aD[nt];
            }
            vs += __shfl_xor(vs, 1); vd += __shfl_xor(vd, 1);
            vs += __shfl_xor(vs, 2); vd += __shfl_xor(vd, 2);
            vs += __shfl_xor(vs, 4); vd += __shfl_xor(vd, 4);
            vs += __shfl_xor(vs, 8); vd += __shfl_xor(vd, 8);
            if (l15 == 0) {
                const int nl = mt * 16 + quad * 4 + r;
                sc_lds[wave][nl] = vs; dc_lds[wave][nl] = vd;
            }
        }
    for (int mt = 0; mt < 4; ++mt)
        for (int nt = 0; nt < 4; ++nt)
            for (int r = 0; r < 4; ++r) {
                const int c = wave * 64 + nt * 16 + l15;
                const int n = mt * 16 + quad * 4 + r;
                tr_lds[c * 72 + n] = f2bf(acc[mt][nt][r]);
            }
    __syncthreads();
    if (t < 128) {
        const int n = t >> 1, h = t & 1;
        s[(size_t)(n0 + n) * 2 + h] = sc_lds[h * 2][n] + sc_lds[h * 2 + 1][n];
        d[(size_t)(n0 + n) * 2 + h] = dc_lds[h * 2][n] + dc_lds[h * 2 + 1][n];
    }
    for (int p = 0; p < 8; ++p) {
        const int idx = p * 256 + t;       // 2048 granules
        const int c = idx >> 3, g = idx & 7;
        *(b16x8*)(Tt + (size_t)c * NN + n0 + g * 8) = *(const b16x8*)&tr_lds[c * 72 + g * 8];
    }
}

// ---------------------------------------------------------------------------
// Kernel 2: fused masked-softmax aggregation (flash-style, bf16 MFMA)
//   grid=(256, jsplit), block=256 (4 waves: (h, f-half))
//   v2: no Tt LDS staging (tile has ZERO intra-block reuse and is L2-resident
//       -> B-fragments straight from global), double-buffered 8KB w_lds with
//       ONE raw barrier per iter (lgkmcnt only, vmcnt never drained),
//       adjacency register-prefetch one tile ahead, XCD chunk-affinity.
// ---------------------------------------------------------------------------
__global__ __launch_bounds__(256, 4) void k_gat(
    const int* __restrict__ adj, const unsigned short* __restrict__ Tt,
    const float* __restrict__ s, const float* __restrict__ d,
    float* __restrict__ num_part,   // [jsplit][NN][CD]
    float* __restrict__ den_part,   // [jsplit][2][NN]
    int jchunk)
{
    __shared__ unsigned short w_lds[2][2 * BI * BJ];   // 16KB, double-buffered

    const int t = threadIdx.x;
    const int wave = t >> 6, lane = t & 63;
    const int l15 = lane & 15, quad = lane >> 4;

    // XCD chunk-affinity: consecutive block ids round-robin XCDs, so give each
    // XCD one j-chunk -> its 32KB/iter Tt tile stays L2-resident against the
    // adjacency stream. Bijective for gridDim.y in {2,4,8}.
    const int flat = blockIdx.y * gridDim.x + blockIdx.x;
    const int xcd = flat & 7, o = flat >> 3;
    const int xpc = 8 / gridDim.y;                    // XCDs per chunk
    const int chunk = xcd / xpc;
    const int ib = (xcd % xpc) * (gridDim.x / xpc) + o;
    const int i0 = ib * BI;
    const int jbase = chunk * jchunk;

    const int wi = t >> 3;          // 0..31 : row within i-tile
    const int j8 = t & 7;           // 0..7  : 8-wide j granule
    const int gi = i0 + wi;
    const float s0 = s[(size_t)gi * 2 + 0];
    const float s1 = s[(size_t)gi * 2 + 1];

    const int h = wave >> 1;        // head
    const int fh = wave & 1;        // f-half
    const int cbase = h * 128 + fh * 64;

    f32x4 acc[2][4] = {};
    float den0 = 0.f, den1 = 0.f;
    const int njt = jchunk / BJ;

    // prefetch iter-0 adjacency (the only HBM-latency item)
    const int* arow = adj + (size_t)gi * NN + j8 * 8;
    int4 a0p = *(const int4*)(arow + jbase);
    int4 a1p = *(const int4*)(arow + jbase + 4);

    int buf = 0;
    for (int jt = 0; jt < njt; ++jt) {
        const int j0 = jbase + jt * BJ;
        // d scores for this tile (small, L1/L2-hot) -- issued FIRST so the
        // exp-phase vmcnt wait leaves the bfr loads below in flight
        const float4* dvp = (const float4*)(d + (size_t)(j0 + j8 * 8) * 2);
        union { float4 v[4]; float f[16]; } dv;
        dv.v[0] = dvp[0]; dv.v[1] = dvp[1]; dv.v[2] = dvp[2]; dv.v[3] = dvp[3];
        // B fragments straight from global Tt (identical values/layout to the
        // old LDS round-trip: Tt[c][j0 + gidx*8 .. +7])
        b16x8 bfr[2][4];
        for (int ks = 0; ks < 2; ++ks)
            for (int nt = 0; nt < 4; ++nt) {
                const int c = cbase + nt * 16 + l15;
                bfr[ks][nt] = *(const b16x8*)(Tt + (size_t)c * NN + j0 + (ks * 4 + quad) * 8);
            }
        // masked exp(leaky) weights from PREFETCHED adjacency
        const int am[8] = {a0p.x, a0p.y, a0p.z, a0p.w, a1p.x, a1p.y, a1p.z, a1p.w};
        union { unsigned short us[8]; b16x8 v; } w0, w1;
        float dp0 = 0.f, dp1 = 0.f;
        for (int e = 0; e < 8; ++e) {
            float x0 = s0 + dv.f[e * 2 + 0];  x0 = x0 > 0.f ? x0 : 0.2f * x0;
            float x1 = s1 + dv.f[e * 2 + 1];  x1 = x1 > 0.f ? x1 : 0.2f * x1;
            const float e0 = am[e] != 0 ? __expf(x0) : 0.f;
            const float e1 = am[e] != 0 ? __expf(x1) : 0.f;
            dp0 += e0; dp1 += e1;
            w0.us[e] = f2bf(e0); w1.us[e] = f2bf(e1);
        }
        den0 += dp0; den1 += dp1;
        const int slot = (j8 ^ (wi & 7)) << 3;
        *(b16x8*)&w_lds[buf][(0 * BI + wi) * BJ + slot] = w0.v;
        *(b16x8*)&w_lds[buf][(1 * BI + wi) * BJ + slot] = w1.v;
        // prefetch next tile's adjacency row (clamped in-bounds; unused at tail)
        {
            const int jn = (jt + 1 < njt) ? j0 + BJ : jbase;
            a0p = *(const int4*)(arow + jn);
            a1p = *(const int4*)(arow + jn + 4);
        }
        // raw barrier: LDS writes visible, vmcnt NOT drained -- bfr + adj
        // prefetch stay in flight across it (the whole point of this version)
        asm volatile("s_waitcnt lgkmcnt(0)" ::: "memory");
        __builtin_amdgcn_s_barrier();
        __builtin_amdgcn_sched_barrier(0);
        // MFMA: num[i, cbase..cbase+63] += w_h @ T
        for (int ks = 0; ks < 2; ++ks) {
            const int gidx = ks * 4 + quad;
            b16x8 af[2];
            for (int mt = 0; mt < 2; ++mt) {
                const int m = mt * 16 + l15;
                af[mt] = *(const b16x8*)&w_lds[buf][(h * BI + m) * BJ + ((gidx ^ (m & 7)) << 3)];
            }
            for (int mt = 0; mt < 2; ++mt)
                for (int nt = 0; nt < 4; ++nt)
                    acc[mt][nt] = __builtin_amdgcn_mfma_f32_16x16x32_bf16(
                        af[mt], bfr[ks][nt], acc[mt][nt], 0, 0, 0);
        }
        buf ^= 1;
    }
    // reduce den over the 8 j8-lanes (lane bits 0..2)
    den0 += __shfl_xor(den0, 1); den0 += __shfl_xor(den0, 2); den0 += __shfl_xor(den0, 4);
    den1 += __shfl_xor(den1, 1); den1 += __shfl_xor(den1, 2); den1 += __shfl_xor(den1, 4);
    if (j8 == 0) {
        den_part[((size_t)chunk * 2 + 0) * NN + gi] = den0;
        den_part[((size_t)chunk * 2 + 1) * NN + gi] = den1;
    }
    float* np_ = num_part + (size_t)chunk * NN * CD;
    for (int mt = 0; mt < 2; ++mt)
        for (int nt = 0; nt < 4; ++nt)
            for (int r = 0; r < 4; ++r) {
                const int n = i0 + mt * 16 + quad * 4 + r;
                const int c = cbase + nt * 16 + l15;
                np_[(size_t)n * CD + c] = acc[mt][nt][r];
            }
}

// ---------------------------------------------------------------------------
// Kernel 3: combine partials, normalize, mean over heads.  grid=4096
// ---------------------------------------------------------------------------
__global__ __launch_bounds__(256) void k_combine(
    const float* __restrict__ num_part, const float* __restrict__ den_part,
    float* __restrict__ out, int jsplit)
{
    const int idx = blockIdx.x * 256 + threadIdx.x;   // NN*FD
    const int n = idx >> 7, f = idx & 127;
    const size_t row = (size_t)n * CD;
    float n0 = 0.f, n1 = 0.f, d0 = 0.f, d1 = 0.f;
    for (int c = 0; c < jsplit; ++c) {
        const size_t base = (size_t)c * NN * CD;
        n0 += num_part[base + row + f];
        n1 += num_part[base + row + 128 + f];
        d0 += den_part[((size_t)c * 2 + 0) * NN + n];
        d1 += den_part[((size_t)c * 2 + 1) * NN + n];
    }
    const float r0 = d0 != 0.f ? n0 / d0 : 0.f;
    const float r1 = d1 != 0.f ? n1 / d1 : 0.f;
    out[idx] = 0.5f * (r0 + r1);
}

// ---------------------------------------------------------------------------
extern "C" void kernel_launch(void* const* d_in, const int* in_sizes, int n_in,
                              void* d_out, int out_size, void* d_ws, size_t ws_size,
                              hipStream_t stream) {
    const float* feat = (const float*)d_in[0];
    const int*   adj  = (const int*)d_in[1];
    const float* W    = (const float*)d_in[2];
    const float* asrc = (const float*)d_in[3];
    const float* adst = (const float*)d_in[4];
    float* out = (float*)d_out;

    // jsplit=4 needs 8MB + 4*8MB = 40MB of ws; fall back to 2 (24MB) if short
    const int jsplit = (ws_size >= ((size_t)40 << 20)) ? 4 : 2;
    const int jchunk = NN / jsplit;

    char* ws = (char*)d_ws;
    unsigned short* Tt = (unsigned short*)ws;                       // 4 MB
    float* s    = (float*)(ws + ((size_t)4 << 20));                 // 64 KB
    float* dsc  = (float*)(ws + ((size_t)4 << 20) + (64 << 10));    // 64 KB
    float* den  = (float*)(ws + ((size_t)4 << 20) + (128 << 10));   // <=256 KB
    float* nump = (float*)(ws + ((size_t)8 << 20));                 // jsplit*8 MB

    k_transform<<<128, 256, 0, stream>>>(feat, W, asrc, adst, Tt, s, dsc);
    k_gat<<<dim3(NN / BI, jsplit), 256, 0, stream>>>(adj, Tt, s, dsc, nump, den, jchunk);
    k_combine<<<NN * FD / 256, 256, 0, stream>>>(nump, den, out, jsplit);
}